// Round 7
// baseline (251.642 us; speedup 1.0000x reference)
//
#include <hip/hip_runtime.h>
#include <stdint.h>

// Problem constants: B=4, C=128, H=W=128, N=9, OC=256, stride=1
#define CIN   128
#define HWSZ  16384
#define NP    9
#define OCH   256

typedef __bf16 bf16_t;
typedef __bf16 bf16x8 __attribute__((ext_vector_type(8)));
typedef float  f32x4  __attribute__((ext_vector_type(4)));
typedef _Float16 f16x4 __attribute__((ext_vector_type(4)));
union MU { uint2 u; f16x4 h; };

// async global->LDS, 16B/lane; LDS dest = wave-uniform base + lane*16.
__device__ __forceinline__ void gll16(const void* g, void* l) {
  __builtin_amdgcn_global_load_lds(
      (const __attribute__((address_space(1))) void*)g,
      (__attribute__((address_space(3))) void*)l, 16, 0, 0);
}

// ---------------------------------------------------------------------------
// B repack, padded fragment order: bt[k8'][o][8] bf16, k8' in [0,160).
// k' = k8'*8+i; cc = k'/160; n = (k'%160)>>4; ci = k'%16; c = cc*16+ci.
// ---------------------------------------------------------------------------
__global__ void k_bt(const float* __restrict__ wc, bf16_t* __restrict__ bt) {
  int k8 = blockIdx.x, og = blockIdx.y, tid = threadIdx.x;
  int i = tid & 7, o = og * 32 + (tid >> 3);
  int kp = k8 * 8 + i;
  int cc = kp / 160, rem = kp % 160;
  int n = rem >> 4, ci = rem & 15;
  int c = cc * 16 + ci;
  float v = (n < 9) ? wc[(o * CIN + c) * NP + n] : 0.f;
  bt[(size_t)k8 * 2048 + o * 8 + i] = (bf16_t)v;
}

// ---------------------------------------------------------------------------
// Offset-conv weight split, MFMA B-fragment order (hi/lo bf16 for 3-term).
// ---------------------------------------------------------------------------
__global__ void k_wf(const float* __restrict__ wc, bf16_t* __restrict__ wf) {
  int chunk = blockIdx.x, nf = blockIdx.y, hl = blockIdx.z;
  int lane = threadIdx.x;
  int l15 = lane & 15, quad = lane >> 4;
  int cg = chunk / 9, t = chunk % 9;
  int o = nf * 16 + l15;
  bf16x8 e;
#pragma unroll
  for (int i = 0; i < 8; ++i) {
    int ch = cg * 32 + quad * 8 + i;
    float w = (o < 18) ? wc[((size_t)o * CIN + ch) * NP + t] : 0.f;
    bf16_t h = (bf16_t)w;
    e[i] = hl ? (bf16_t)(w - (float)h) : h;
  }
  *(bf16x8*)((char*)wf + ((((size_t)hl * 36 + chunk) * 2 + nf) * 64 + lane) * 16) = e;
}

// ---------------------------------------------------------------------------
// Offset conv AS MFMA (3-term bf16 split) + fused bilinear meta.
// Block = (bb, ii): M=128 pix, N=18(pad 32), K=1152. Grid 512 -> with 57KB
// LDS and tiny acc, 2 blocks/CU (round-5 ran 1/CU and was latency-bound).
// ---------------------------------------------------------------------------
__global__ __launch_bounds__(512, 4) void k_off(
    const float* __restrict__ x, const bf16_t* __restrict__ wf,
    const float* __restrict__ bp, int* __restrict__ midx, uint2* __restrict__ mwh)
{
  __shared__ __align__(16) char smem[57024];   // 396 entries x 144B
  int blk = (blockIdx.x & 7) * 64 + (blockIdx.x >> 3);   // XCD swizzle (512)
  int bb = blk >> 7, ii = blk & 127;
  int tid = threadIdx.x;
  int wave = tid >> 6, lane = tid & 63;
  int l15 = lane & 15, quad = lane >> 4;

  f32x4 acc[2];
  acc[0] = (f32x4){0.f, 0.f, 0.f, 0.f};
  acc[1] = (f32x4){0.f, 0.f, 0.f, 0.f};

#pragma unroll 1
  for (int cg = 0; cg < 4; ++cg) {
    __syncthreads();   // previous cg's fragment reads drained
    for (int u = tid; u < 396; u += 512) {
      int row = u / 132, col = u % 132;
      int gr = ii - 1 + row, gc = col - 1;
      bool ok = ((unsigned)gr < 128u) && ((unsigned)gc < 128u);
      const float* gp = x + ((size_t)(bb * CIN + cg * 32)) * HWSZ + gr * 128 + gc;
      float v[32];
#pragma unroll
      for (int ch = 0; ch < 32; ++ch) v[ch] = ok ? gp[(size_t)ch * HWSZ] : 0.f;
#pragma unroll
      for (int q8 = 0; q8 < 8; ++q8)
        *(f32x4*)(smem + (size_t)u * 144 + q8 * 16) =
            (f32x4){v[q8 * 4], v[q8 * 4 + 1], v[q8 * 4 + 2], v[q8 * 4 + 3]};
    }
    __syncthreads();
#pragma unroll
    for (int t = 0; t < 9; ++t) {
      int chunk = cg * 9 + t, dy = t / 3, dx = t % 3;
      const char* wb = (const char*)wf;
      bf16x8 bh0 = *(const bf16x8*)(wb + (((size_t)chunk) * 2 + 0) * 1024 + lane * 16);
      bf16x8 bh1 = *(const bf16x8*)(wb + (((size_t)chunk) * 2 + 1) * 1024 + lane * 16);
      bf16x8 bl0 = *(const bf16x8*)(wb + (((size_t)36 + chunk) * 2 + 0) * 1024 + lane * 16);
      bf16x8 bl1 = *(const bf16x8*)(wb + (((size_t)36 + chunk) * 2 + 1) * 1024 + lane * 16);
      int m = wave * 16 + l15;                 // = j
      int ent = dy * 132 + m + dx;
      f32x4 xlo = *(const f32x4*)(smem + (size_t)ent * 144 + quad * 32);
      f32x4 xhi = *(const f32x4*)(smem + (size_t)ent * 144 + quad * 32 + 16);
      bf16x8 ah, al;
#pragma unroll
      for (int i = 0; i < 4; ++i) {
        float v0 = xlo[i], v1 = xhi[i];
        bf16_t h0 = (bf16_t)v0, h1 = (bf16_t)v1;
        ah[i] = h0; ah[i + 4] = h1;
        al[i] = (bf16_t)(v0 - (float)h0);
        al[i + 4] = (bf16_t)(v1 - (float)h1);
      }
      acc[0] = __builtin_amdgcn_mfma_f32_16x16x32_bf16(ah, bh0, acc[0], 0, 0, 0);
      acc[0] = __builtin_amdgcn_mfma_f32_16x16x32_bf16(ah, bl0, acc[0], 0, 0, 0);
      acc[0] = __builtin_amdgcn_mfma_f32_16x16x32_bf16(al, bh0, acc[0], 0, 0, 0);
      acc[1] = __builtin_amdgcn_mfma_f32_16x16x32_bf16(ah, bh1, acc[1], 0, 0, 0);
      acc[1] = __builtin_amdgcn_mfma_f32_16x16x32_bf16(ah, bl1, acc[1], 0, 0, 0);
      acc[1] = __builtin_amdgcn_mfma_f32_16x16x32_bf16(al, bh1, acc[1], 0, 0, 0);
    }
  }

  // ---- epilogue: D -> exch -> meta
  __syncthreads();
  float* exch = (float*)smem;   // 128 x 20 floats
#pragma unroll
  for (int nf = 0; nf < 2; ++nf) {
    int o = nf * 16 + l15;
    if (o < 18) {
#pragma unroll
      for (int r = 0; r < 4; ++r)
        exch[(wave * 16 + quad * 4 + r) * 20 + o] = acc[nf][r];
    }
  }
  __syncthreads();
  if (tid < 128) {
    int j = tid;
    float a18[18];
#pragma unroll
    for (int o = 0; o < 18; ++o) a18[o] = exch[j * 20 + o] + bp[o];
#pragma unroll
    for (int n = 0; n < NP; ++n) {
      float offx = a18[n];
      float offy = a18[9 + n];
      float px = (float)ii + (float)(n / 3) + offx;
      float py = (float)j  + (float)(n % 3) + offy;
      float f0 = floorf(px), f1 = f0 + 1.f;
      float h0 = floorf(py), h1 = h0 + 1.f;
      int r0 = (int)fminf(fmaxf(f0, 0.f), 127.f);
      int r1 = (int)fminf(fmaxf(f1, 0.f), 127.f);
      int c0 = (int)fminf(fmaxf(h0, 0.f), 127.f);
      int c1 = (int)fminf(fmaxf(h1, 0.f), 127.f);
      float pxc = fminf(fmaxf(px, 0.f), 127.f);
      float pyc = fminf(fmaxf(py, 0.f), 127.f);
      float glt = (1.f + ((float)r0 - pxc)) * (1.f + ((float)c0 - pyc));
      float grb = (1.f - ((float)r1 - pxc)) * (1.f - ((float)c1 - pyc));
      float glb = (1.f + ((float)r0 - pxc)) * (1.f - ((float)c1 - pyc));
      float grt = (1.f - ((float)r1 - pxc)) * (1.f + ((float)c0 - pyc));
      int qb = (c0 < 126) ? c0 : 126;
      bool s0 = (c0 != qb), s1 = (c1 != qb);
      float wA = (s0 ? 0.f : glt) + (s1 ? 0.f : glb);
      float wB = (s0 ? glt : 0.f) + (s1 ? glb : 0.f);
      float wC = (s0 ? 0.f : grt) + (s1 ? 0.f : grb);
      float wD = (s0 ? grt : 0.f) + (s1 ? grb : 0.f);
      int base = ((bb * 128 + ii) * NP + n) * 128 + j;
      midx[base] = r0 | (r1 << 8) | (qb << 16);
      MU mu;
      mu.h = (f16x4){(_Float16)wA, (_Float16)wB, (_Float16)wC, (_Float16)wD};
      mwh[base] = mu.u;
    }
  }
}

// ---------------------------------------------------------------------------
// Fused gather+GEMM. Block = (bb, ii): M=128 pix, N=256 o, K=1280 padded.
// Grid 512; LDS = exactly 80 KiB -> 2 blocks/CU; launch_bounds(512,4) caps
// regs at 128 (acc is 64). XP: 2 planes x [8row][128col] x 16B (8ch bf16).
// A slice: [4 k8][128 pix] x 16B, double-buffered -> conflict-free by
// construction (consecutive-pix b128). Meta held in 15 regs (same 5 values
// for all cc chunks). Per slice: 1 fragment-entry per thread (4 b128 corner
// reads + 32 fma), barrier, gll_B(st+1), 16 MFMA per wave.
// ---------------------------------------------------------------------------
__global__ __launch_bounds__(512, 4) void k_gg(
    const float* __restrict__ x, const bf16_t* __restrict__ bt,
    const int* __restrict__ midx, const uint2* __restrict__ mwh,
    float* __restrict__ out)
{
  // XP@0 (2x16384) | A@32768 (2x8192) | B@49152 (2x16384) = 81920
  __shared__ __align__(16) char smem[81920];
  char* XP = smem;
  char* Al = smem + 32768;
  char* Bl = smem + 49152;

  int blk = (blockIdx.x & 7) * 64 + (blockIdx.x >> 3);   // XCD swizzle (512)
  int bb = blk >> 7, ii = blk & 127;
  int tid = threadIdx.x;
  int wave = tid >> 6, lane = tid & 63;
  int l15 = lane & 15, quad = lane >> 4;
  int pix = tid & 127;        // j
  int qq  = tid >> 7;         // 0..3: nh = qq>>1, plane = qq&1
  int nh = qq >> 1, plane = qq & 1;

  const float* xg = x + (size_t)bb * CIN * HWSZ;

  // ---- meta preload: 5 slices' worth, constant across all cc chunks
  int   pmi[5];
  uint2 pmw[5];
#pragma unroll
  for (int s = 0; s < 5; ++s) {
    int n = 2 * s + nh;
    if (n < 9) {
      int g = ((bb * 128 + ii) * NP + n) * 128 + pix;
      pmi[s] = midx[g];
      pmw[s] = mwh[g];
    } else {
      pmi[s] = -1;
      pmw[s] = make_uint2(0u, 0u);
    }
  }

  // stage one 16-ch slab of the 8-row window (rows ii-2..ii+5, clamped rows
  // are never addressed by in-window interp since r0,r1 are pre-clamped).
  auto stage_x = [&](int cc) {
    int c0 = cc * 16;
#pragma unroll 2
    for (int k = 0; k < 4; ++k) {
      int e = tid + k * 512;          // 0..2047
      int pl = e >> 10;
      int rem = e & 1023;
      int row = rem >> 7, col = rem & 127;
      int r = min(127, max(0, ii - 2 + row));
      const float* gp = xg + (size_t)(c0 + pl * 8) * HWSZ + r * 128 + col;
      bf16x8 ev;
#pragma unroll
      for (int i = 0; i < 8; ++i) ev[i] = (bf16_t)gp[(size_t)i * HWSZ];
      *(bf16x8*)(XP + pl * 16384 + (row * 128 + col) * 16) = ev;
    }
  };

  auto gll_B = [&](int stn) {
    const char* src = (const char*)bt + (size_t)stn * 16384 + tid * 16;
    char* dst = Bl + (stn & 1) * 16384 + tid * 16;
    gll16(src, dst);
    gll16(src + 8192, dst + 8192);
  };

  stage_x(0);
  gll_B(0);

  f32x4 acc[8][2];
#pragma unroll
  for (int i = 0; i < 8; ++i)
#pragma unroll
    for (int j2 = 0; j2 < 2; ++j2) acc[i][j2] = (f32x4){0.f, 0.f, 0.f, 0.f};

  __syncthreads();   // stage(0) visible; B(0) drained

#pragma unroll 1
  for (int cc = 0; cc < 8; ++cc) {
    if (cc > 0) __syncthreads();   // stage(cc) visible; gll_B drained
#pragma unroll
    for (int s = 0; s < 5; ++s) {
      int st = cc * 5 + s;
      char* Abuf = Al + (st & 1) * 8192;

      // ---- interp: one fragment-entry per thread
      {
        bf16x8 av = {};
        int im = pmi[s];
        if (im >= 0) {
          MU mu; mu.u = pmw[s];
          float wA = (float)mu.h[0], wB = (float)mu.h[1];
          float wC = (float)mu.h[2], wD = (float)mu.h[3];
          int r0 = im & 255, r1 = (im >> 8) & 255, qb = (im >> 16) & 255;
          int s0 = r0 - ii + 2, s1 = r1 - ii + 2;
          if (((unsigned)s0 < 8u) & ((unsigned)s1 < 8u)) {
            const char* pb = XP + plane * 16384;
            bf16x8 a0 = *(const bf16x8*)(pb + (s0 * 128 + qb) * 16);
            bf16x8 a1 = *(const bf16x8*)(pb + (s0 * 128 + qb + 1) * 16);
            bf16x8 b0 = *(const bf16x8*)(pb + (s1 * 128 + qb) * 16);
            bf16x8 b1 = *(const bf16x8*)(pb + (s1 * 128 + qb + 1) * 16);
#pragma unroll
            for (int it = 0; it < 8; ++it)
              av[it] = (bf16_t)(wA * (float)a0[it] + wB * (float)a1[it] +
                                wC * (float)b0[it] + wD * (float)b1[it]);
          } else {   // exact fp32 fallback, ~never taken
            const float* gb = xg + (size_t)(cc * 16 + plane * 8) * HWSZ;
            const float* q0 = gb + r0 * 128 + qb;
            const float* q1 = gb + r1 * 128 + qb;
#pragma unroll
            for (int it = 0; it < 8; ++it) {
              av[it] = (bf16_t)(wA * q0[0] + wB * q0[1] + wC * q1[0] + wD * q1[1]);
              q0 += HWSZ; q1 += HWSZ;
            }
          }
        }
        *(bf16x8*)(Abuf + (qq * 128 + pix) * 16) = av;
      }

      __syncthreads();   // A(st) ready; B(st) drained
      if (st < 39) gll_B(st + 1);   // lands under MFMA + next interp

      // ---- MFMA: wave owns 128m x 32o
      {
        const char* Bb = Bl + (st & 1) * 16384;
        bf16x8 bfr[2];
#pragma unroll
        for (int of = 0; of < 2; ++of)
          bfr[of] = *(const bf16x8*)(Bb + quad * 4096 + (wave * 32 + of * 16 + l15) * 16);
#pragma unroll
        for (int mf = 0; mf < 8; ++mf) {
          bf16x8 af = *(const bf16x8*)(Abuf + (quad * 128 + mf * 16 + l15) * 16);
#pragma unroll
          for (int of = 0; of < 2; ++of)
            acc[mf][of] = __builtin_amdgcn_mfma_f32_16x16x32_bf16(
                af, bfr[of], acc[mf][of], 0, 0, 0);
        }
      }
    }
    if (cc < 7) stage_x(cc + 1);   // window reads all drained at slice barrier
  }

  // ---- epilogue: per-wave transpose 16o x 128m pieces, coalesced stores
  __syncthreads();
  float* pw = (float*)smem + wave * 2112;   // 16 x 132 floats per wave
#pragma unroll
  for (int of = 0; of < 2; ++of) {
#pragma unroll
    for (int mf = 0; mf < 8; ++mf)
      *(f32x4*)(pw + l15 * 132 + mf * 16 + quad * 4) = acc[mf][of];
#pragma unroll
    for (int g = 0; g < 8; ++g) {
      int o_loc = (g & 3) * 4 + quad;
      int mcol = (g >> 2) * 64 + l15 * 4;
      f32x4 v = *(const f32x4*)(pw + o_loc * 132 + mcol);
      int o = wave * 32 + of * 16 + o_loc;
      *(f32x4*)(out + ((size_t)(bb * OCH + o) * 128 + ii) * 128 + mcol) = v;
    }
  }
}

// ---------------------------------------------------------------------------
extern "C" void kernel_launch(void* const* d_in, const int* in_sizes, int n_in,
                              void* d_out, int out_size, void* d_ws, size_t ws_size,
                              hipStream_t stream) {
  const float* x  = (const float*)d_in[0];
  const float* wp = (const float*)d_in[1];
  const float* bp = (const float*)d_in[2];
  const float* wc = (const float*)d_in[3];
  float* out = (float*)d_out;

  bf16_t* BT   = (bf16_t*)d_ws;                              //   655,360 B
  bf16_t* WF   = (bf16_t*)((char*)d_ws + 671744);            //   147,456 B
  int*    MIDX = (int*)   ((char*)d_ws + (1u << 20));        // 2,359,296 B
  uint2*  MWH  = (uint2*) ((char*)d_ws + (4u << 20));        // 4,718,592 B -> 8.5MB

  k_bt<<<dim3(160, 8), 256, 0, stream>>>(wc, BT);
  k_wf<<<dim3(36, 2, 2), 64, 0, stream>>>(wp, WF);
  k_off<<<512, 512, 0, stream>>>(x, WF, bp, MIDX, MWH);
  k_gg<<<512, 512, 0, stream>>>(x, BT, MIDX, MWH, out);
}

// Round 9
// 202.690 us; speedup vs baseline: 1.2415x; 1.2415x over previous
//
#include <hip/hip_runtime.h>
#include <stdint.h>

// Problem constants: B=4, C=128, H=W=128, N=9, OC=256, stride=1
#define CIN   128
#define HWSZ  16384
#define NP    9
#define OCH   256

typedef __bf16 bf16_t;
typedef __bf16 bf16x8 __attribute__((ext_vector_type(8)));
typedef float  f32x4  __attribute__((ext_vector_type(4)));
typedef _Float16 f16x4 __attribute__((ext_vector_type(4)));
union MU { uint2 u; f16x4 h; };

// async global->LDS, 16B/lane; LDS dest = wave-uniform base + lane*16.
__device__ __forceinline__ void gll16(const void* g, void* l) {
  __builtin_amdgcn_global_load_lds(
      (const __attribute__((address_space(1))) void*)g,
      (__attribute__((address_space(3))) void*)l, 16, 0, 0);
}

// ---------------------------------------------------------------------------
// B repack, padded fragment order: bt[k8'][o][8] bf16, k8' in [0,160).
// k' = k8'*8+i; cc = k'/160; n = (k'%160)>>4; ci = k'%16; c = cc*16+ci.
// ---------------------------------------------------------------------------
__global__ void k_bt(const float* __restrict__ wc, bf16_t* __restrict__ bt) {
  int k8 = blockIdx.x, og = blockIdx.y, tid = threadIdx.x;
  int i = tid & 7, o = og * 32 + (tid >> 3);
  int kp = k8 * 8 + i;
  int cc = kp / 160, rem = kp % 160;
  int n = rem >> 4, ci = rem & 15;
  int c = cc * 16 + ci;
  float v = (n < 9) ? wc[(o * CIN + c) * NP + n] : 0.f;
  bt[(size_t)k8 * 2048 + o * 8 + i] = (bf16_t)v;
}

// ---------------------------------------------------------------------------
// Offset-conv weight split, MFMA B-fragment order (hi/lo bf16 for 3-term).
// ---------------------------------------------------------------------------
__global__ void k_wf(const float* __restrict__ wc, bf16_t* __restrict__ wf) {
  int chunk = blockIdx.x, nf = blockIdx.y, hl = blockIdx.z;
  int lane = threadIdx.x;
  int l15 = lane & 15, quad = lane >> 4;
  int cg = chunk / 9, t = chunk % 9;
  int o = nf * 16 + l15;
  bf16x8 e;
#pragma unroll
  for (int i = 0; i < 8; ++i) {
    int ch = cg * 32 + quad * 8 + i;
    float w = (o < 18) ? wc[((size_t)o * CIN + ch) * NP + t] : 0.f;
    bf16_t h = (bf16_t)w;
    e[i] = hl ? (bf16_t)(w - (float)h) : h;
  }
  *(bf16x8*)((char*)wf + ((((size_t)hl * 36 + chunk) * 2 + nf) * 64 + lane) * 16) = e;
}

// ---------------------------------------------------------------------------
// Offset conv AS MFMA (3-term bf16 split) + fused bilinear meta.
// Block = (bb, ii): M=128 pix, N=18(pad 32), K=1152. 57KB LDS -> 2 blocks/CU.
// NOTE: __launch_bounds__ 2nd arg is MIN BLOCKS PER CU on this compiler
// (round-7: arg=4 with 8-wave blocks -> 64-VGPR cap -> acc spilled, 257MB
// scratch traffic). arg=2 -> 128-VGPR cap, matching round-5's no-spill alloc.
// ---------------------------------------------------------------------------
__global__ __launch_bounds__(512, 2) void k_off(
    const float* __restrict__ x, const bf16_t* __restrict__ wf,
    const float* __restrict__ bp, int* __restrict__ midx, uint2* __restrict__ mwh)
{
  __shared__ __align__(16) char smem[57024];   // 396 entries x 144B
  int blk = (blockIdx.x & 7) * 64 + (blockIdx.x >> 3);   // XCD swizzle (512)
  int bb = blk >> 7, ii = blk & 127;
  int tid = threadIdx.x;
  int wave = tid >> 6, lane = tid & 63;
  int l15 = lane & 15, quad = lane >> 4;

  f32x4 acc[2];
  acc[0] = (f32x4){0.f, 0.f, 0.f, 0.f};
  acc[1] = (f32x4){0.f, 0.f, 0.f, 0.f};

#pragma unroll 1
  for (int cg = 0; cg < 4; ++cg) {
    __syncthreads();   // previous cg's fragment reads drained
    for (int u = tid; u < 396; u += 512) {
      int row = u / 132, col = u % 132;
      int gr = ii - 1 + row, gc = col - 1;
      bool ok = ((unsigned)gr < 128u) && ((unsigned)gc < 128u);
      const float* gp = x + ((size_t)(bb * CIN + cg * 32)) * HWSZ + gr * 128 + gc;
      float v[32];
#pragma unroll
      for (int ch = 0; ch < 32; ++ch) v[ch] = ok ? gp[(size_t)ch * HWSZ] : 0.f;
#pragma unroll
      for (int q8 = 0; q8 < 8; ++q8)
        *(f32x4*)(smem + (size_t)u * 144 + q8 * 16) =
            (f32x4){v[q8 * 4], v[q8 * 4 + 1], v[q8 * 4 + 2], v[q8 * 4 + 3]};
    }
    __syncthreads();
#pragma unroll
    for (int t = 0; t < 9; ++t) {
      int chunk = cg * 9 + t, dy = t / 3, dx = t % 3;
      const char* wb = (const char*)wf;
      bf16x8 bh0 = *(const bf16x8*)(wb + (((size_t)chunk) * 2 + 0) * 1024 + lane * 16);
      bf16x8 bh1 = *(const bf16x8*)(wb + (((size_t)chunk) * 2 + 1) * 1024 + lane * 16);
      bf16x8 bl0 = *(const bf16x8*)(wb + (((size_t)36 + chunk) * 2 + 0) * 1024 + lane * 16);
      bf16x8 bl1 = *(const bf16x8*)(wb + (((size_t)36 + chunk) * 2 + 1) * 1024 + lane * 16);
      int m = wave * 16 + l15;                 // = j
      int ent = dy * 132 + m + dx;
      f32x4 xlo = *(const f32x4*)(smem + (size_t)ent * 144 + quad * 32);
      f32x4 xhi = *(const f32x4*)(smem + (size_t)ent * 144 + quad * 32 + 16);
      bf16x8 ah, al;
#pragma unroll
      for (int i = 0; i < 4; ++i) {
        float v0 = xlo[i], v1 = xhi[i];
        bf16_t h0 = (bf16_t)v0, h1 = (bf16_t)v1;
        ah[i] = h0; ah[i + 4] = h1;
        al[i] = (bf16_t)(v0 - (float)h0);
        al[i + 4] = (bf16_t)(v1 - (float)h1);
      }
      acc[0] = __builtin_amdgcn_mfma_f32_16x16x32_bf16(ah, bh0, acc[0], 0, 0, 0);
      acc[0] = __builtin_amdgcn_mfma_f32_16x16x32_bf16(ah, bl0, acc[0], 0, 0, 0);
      acc[0] = __builtin_amdgcn_mfma_f32_16x16x32_bf16(al, bh0, acc[0], 0, 0, 0);
      acc[1] = __builtin_amdgcn_mfma_f32_16x16x32_bf16(ah, bh1, acc[1], 0, 0, 0);
      acc[1] = __builtin_amdgcn_mfma_f32_16x16x32_bf16(ah, bl1, acc[1], 0, 0, 0);
      acc[1] = __builtin_amdgcn_mfma_f32_16x16x32_bf16(al, bh1, acc[1], 0, 0, 0);
    }
  }

  // ---- epilogue: D -> exch -> meta
  __syncthreads();
  float* exch = (float*)smem;   // 128 x 20 floats
#pragma unroll
  for (int nf = 0; nf < 2; ++nf) {
    int o = nf * 16 + l15;
    if (o < 18) {
#pragma unroll
      for (int r = 0; r < 4; ++r)
        exch[(wave * 16 + quad * 4 + r) * 20 + o] = acc[nf][r];
    }
  }
  __syncthreads();
  if (tid < 128) {
    int j = tid;
    float a18[18];
#pragma unroll
    for (int o = 0; o < 18; ++o) a18[o] = exch[j * 20 + o] + bp[o];
#pragma unroll
    for (int n = 0; n < NP; ++n) {
      float offx = a18[n];
      float offy = a18[9 + n];
      float px = (float)ii + (float)(n / 3) + offx;
      float py = (float)j  + (float)(n % 3) + offy;
      float f0 = floorf(px), f1 = f0 + 1.f;
      float h0 = floorf(py), h1 = h0 + 1.f;
      int r0 = (int)fminf(fmaxf(f0, 0.f), 127.f);
      int r1 = (int)fminf(fmaxf(f1, 0.f), 127.f);
      int c0 = (int)fminf(fmaxf(h0, 0.f), 127.f);
      int c1 = (int)fminf(fmaxf(h1, 0.f), 127.f);
      float pxc = fminf(fmaxf(px, 0.f), 127.f);
      float pyc = fminf(fmaxf(py, 0.f), 127.f);
      float glt = (1.f + ((float)r0 - pxc)) * (1.f + ((float)c0 - pyc));
      float grb = (1.f - ((float)r1 - pxc)) * (1.f - ((float)c1 - pyc));
      float glb = (1.f + ((float)r0 - pxc)) * (1.f - ((float)c1 - pyc));
      float grt = (1.f - ((float)r1 - pxc)) * (1.f + ((float)c0 - pyc));
      int qb = (c0 < 126) ? c0 : 126;
      bool s0 = (c0 != qb), s1 = (c1 != qb);
      float wA = (s0 ? 0.f : glt) + (s1 ? 0.f : glb);
      float wB = (s0 ? glt : 0.f) + (s1 ? glb : 0.f);
      float wC = (s0 ? 0.f : grt) + (s1 ? 0.f : grb);
      float wD = (s0 ? grt : 0.f) + (s1 ? grb : 0.f);
      int base = ((bb * 128 + ii) * NP + n) * 128 + j;
      midx[base] = r0 | (r1 << 8) | (qb << 16);
      MU mu;
      mu.h = (f16x4){(_Float16)wA, (_Float16)wB, (_Float16)wC, (_Float16)wD};
      mwh[base] = mu.u;
    }
  }
}

// ---------------------------------------------------------------------------
// Fused gather+GEMM. Block = (bb, ii): M=128 pix, N=256 o, K=1280 padded.
// Grid 512; LDS = exactly 80 KiB -> 2 blocks/CU; launch_bounds(512,2) gives
// the 128-VGPR cap (acc is 64; round-5 alloc'd 128 with zero spill).
// XP: 2 planes x [8row][128col] x 16B (8ch bf16). A slice: [4 k8][128 pix]
// x 16B double-buffered (conflict-free b128). Meta in 15 regs.
// ---------------------------------------------------------------------------
__global__ __launch_bounds__(512, 2) void k_gg(
    const float* __restrict__ x, const bf16_t* __restrict__ bt,
    const int* __restrict__ midx, const uint2* __restrict__ mwh,
    float* __restrict__ out)
{
  // XP@0 (2x16384) | A@32768 (2x8192) | B@49152 (2x16384) = 81920
  __shared__ __align__(16) char smem[81920];
  char* XP = smem;
  char* Al = smem + 32768;
  char* Bl = smem + 49152;

  int blk = (blockIdx.x & 7) * 64 + (blockIdx.x >> 3);   // XCD swizzle (512)
  int bb = blk >> 7, ii = blk & 127;
  int tid = threadIdx.x;
  int wave = tid >> 6, lane = tid & 63;
  int l15 = lane & 15, quad = lane >> 4;
  int pix = tid & 127;        // j
  int qq  = tid >> 7;         // 0..3: nh = qq>>1, plane = qq&1
  int nh = qq >> 1, plane = qq & 1;

  const float* xg = x + (size_t)bb * CIN * HWSZ;

  // ---- meta preload: 5 slices' worth, constant across all cc chunks
  int   pmi[5];
  uint2 pmw[5];
#pragma unroll
  for (int s = 0; s < 5; ++s) {
    int n = 2 * s + nh;
    if (n < 9) {
      int g = ((bb * 128 + ii) * NP + n) * 128 + pix;
      pmi[s] = midx[g];
      pmw[s] = mwh[g];
    } else {
      pmi[s] = -1;
      pmw[s] = make_uint2(0u, 0u);
    }
  }

  // stage one 16-ch slab of the 8-row window (rows ii-2..ii+5, clamped rows
  // are never addressed by in-window interp since r0,r1 are pre-clamped).
  auto stage_x = [&](int cc) {
    int c0 = cc * 16;
#pragma unroll 2
    for (int k = 0; k < 4; ++k) {
      int e = tid + k * 512;          // 0..2047
      int pl = e >> 10;
      int rem = e & 1023;
      int row = rem >> 7, col = rem & 127;
      int r = min(127, max(0, ii - 2 + row));
      const float* gp = xg + (size_t)(c0 + pl * 8) * HWSZ + r * 128 + col;
      bf16x8 ev;
#pragma unroll
      for (int i = 0; i < 8; ++i) ev[i] = (bf16_t)gp[(size_t)i * HWSZ];
      *(bf16x8*)(XP + pl * 16384 + (row * 128 + col) * 16) = ev;
    }
  };

  auto gll_B = [&](int stn) {
    const char* src = (const char*)bt + (size_t)stn * 16384 + tid * 16;
    char* dst = Bl + (stn & 1) * 16384 + tid * 16;
    gll16(src, dst);
    gll16(src + 8192, dst + 8192);
  };

  stage_x(0);
  gll_B(0);

  f32x4 acc[8][2];
#pragma unroll
  for (int i = 0; i < 8; ++i)
#pragma unroll
    for (int j2 = 0; j2 < 2; ++j2) acc[i][j2] = (f32x4){0.f, 0.f, 0.f, 0.f};

  __syncthreads();   // stage(0) visible; B(0) drained

#pragma unroll 1
  for (int cc = 0; cc < 8; ++cc) {
    if (cc > 0) __syncthreads();   // stage(cc) visible; gll_B drained
#pragma unroll
    for (int s = 0; s < 5; ++s) {
      int st = cc * 5 + s;
      char* Abuf = Al + (st & 1) * 8192;

      // ---- interp: one fragment-entry per thread
      {
        bf16x8 av = {};
        int im = pmi[s];
        if (im >= 0) {
          MU mu; mu.u = pmw[s];
          float wA = (float)mu.h[0], wB = (float)mu.h[1];
          float wC = (float)mu.h[2], wD = (float)mu.h[3];
          int r0 = im & 255, r1 = (im >> 8) & 255, qb = (im >> 16) & 255;
          int s0 = r0 - ii + 2, s1 = r1 - ii + 2;
          if (((unsigned)s0 < 8u) & ((unsigned)s1 < 8u)) {
            const char* pb = XP + plane * 16384;
            bf16x8 a0 = *(const bf16x8*)(pb + (s0 * 128 + qb) * 16);
            bf16x8 a1 = *(const bf16x8*)(pb + (s0 * 128 + qb + 1) * 16);
            bf16x8 b0 = *(const bf16x8*)(pb + (s1 * 128 + qb) * 16);
            bf16x8 b1 = *(const bf16x8*)(pb + (s1 * 128 + qb + 1) * 16);
#pragma unroll
            for (int it = 0; it < 8; ++it)
              av[it] = (bf16_t)(wA * (float)a0[it] + wB * (float)a1[it] +
                                wC * (float)b0[it] + wD * (float)b1[it]);
          } else {   // exact fp32 fallback, ~never taken
            const float* gb = xg + (size_t)(cc * 16 + plane * 8) * HWSZ;
            const float* q0 = gb + r0 * 128 + qb;
            const float* q1 = gb + r1 * 128 + qb;
#pragma unroll
            for (int it = 0; it < 8; ++it) {
              av[it] = (bf16_t)(wA * q0[0] + wB * q0[1] + wC * q1[0] + wD * q1[1]);
              q0 += HWSZ; q1 += HWSZ;
            }
          }
        }
        *(bf16x8*)(Abuf + (qq * 128 + pix) * 16) = av;
      }

      __syncthreads();   // A(st) ready; B(st) drained
      if (st < 39) gll_B(st + 1);   // lands under MFMA + next interp

      // ---- MFMA: wave owns 128m x 32o
      {
        const char* Bb = Bl + (st & 1) * 16384;
        bf16x8 bfr[2];
#pragma unroll
        for (int of = 0; of < 2; ++of)
          bfr[of] = *(const bf16x8*)(Bb + quad * 4096 + (wave * 32 + of * 16 + l15) * 16);
#pragma unroll
        for (int mf = 0; mf < 8; ++mf) {
          bf16x8 af = *(const bf16x8*)(Abuf + (quad * 128 + mf * 16 + l15) * 16);
#pragma unroll
          for (int of = 0; of < 2; ++of)
            acc[mf][of] = __builtin_amdgcn_mfma_f32_16x16x32_bf16(
                af, bfr[of], acc[mf][of], 0, 0, 0);
        }
      }
    }
    if (cc < 7) stage_x(cc + 1);   // window reads all drained at slice barrier
  }

  // ---- epilogue: per-wave transpose 16o x 128m pieces, coalesced stores
  __syncthreads();
  float* pw = (float*)smem + wave * 2112;   // 16 x 132 floats per wave
#pragma unroll
  for (int of = 0; of < 2; ++of) {
#pragma unroll
    for (int mf = 0; mf < 8; ++mf)
      *(f32x4*)(pw + l15 * 132 + mf * 16 + quad * 4) = acc[mf][of];
#pragma unroll
    for (int g = 0; g < 8; ++g) {
      int o_loc = (g & 3) * 4 + quad;
      int mcol = (g >> 2) * 64 + l15 * 4;
      f32x4 v = *(const f32x4*)(pw + o_loc * 132 + mcol);
      int o = wave * 32 + of * 16 + o_loc;
      *(f32x4*)(out + ((size_t)(bb * OCH + o) * 128 + ii) * 128 + mcol) = v;
    }
  }
}

// ---------------------------------------------------------------------------
extern "C" void kernel_launch(void* const* d_in, const int* in_sizes, int n_in,
                              void* d_out, int out_size, void* d_ws, size_t ws_size,
                              hipStream_t stream) {
  const float* x  = (const float*)d_in[0];
  const float* wp = (const float*)d_in[1];
  const float* bp = (const float*)d_in[2];
  const float* wc = (const float*)d_in[3];
  float* out = (float*)d_out;

  bf16_t* BT   = (bf16_t*)d_ws;                              //   655,360 B
  bf16_t* WF   = (bf16_t*)((char*)d_ws + 671744);            //   147,456 B
  int*    MIDX = (int*)   ((char*)d_ws + (1u << 20));        // 2,359,296 B
  uint2*  MWH  = (uint2*) ((char*)d_ws + (4u << 20));        // 4,718,592 B -> 8.5MB

  k_bt<<<dim3(160, 8), 256, 0, stream>>>(wc, BT);
  k_wf<<<dim3(36, 2, 2), 64, 0, stream>>>(wp, WF);
  k_off<<<512, 512, 0, stream>>>(x, WF, bp, MIDX, MWH);
  k_gg<<<512, 512, 0, stream>>>(x, BT, MIDX, MWH, out);
}